// Round 14
// baseline (1218.850 us; speedup 1.0000x reference)
//
#include <hip/hip_runtime.h>
#include <hip/hip_bf16.h>

typedef unsigned short u16;
typedef __attribute__((ext_vector_type(8))) unsigned short us8;
typedef __attribute__((ext_vector_type(8))) short mfma_in8;   // 8 bf16 in 4 VGPRs
typedef __attribute__((ext_vector_type(4))) float f32x4;

#define NL 6
#define NH 6
#define NE 384
#define NHS 64
#define NT 256
#define NB 64
#define NV 65
#define NM (NB * NT)          // 16384 tokens
#define SCALE 0.051031036307982884f   // 384^-0.5
#define VTP 264               // V^T LDS row stride (u16)
#define PSP 44                // P-tile LDS row stride (u16)

static __device__ __forceinline__ float bf2f(u16 u) {
    return __uint_as_float(((unsigned int)u) << 16);
}
static __device__ __forceinline__ u16 f2bf(float f) {
    unsigned int x = __float_as_uint(f);
    unsigned int r = x + 0x7fffu + ((x >> 16) & 1u);   // RNE
    return (u16)(r >> 16);
}
static __device__ __forceinline__ void llds16(const u16* g, u16* l) {
    __builtin_amdgcn_global_load_lds(
        (const __attribute__((address_space(1))) void*)g,
        (__attribute__((address_space(3))) void*)l, 16, 0, 0);
}

// ---------------- embedding: x(bf16) = tok_emb[idx] + pos_emb --------------------
__global__ __launch_bounds__(256)
void embed_kernel(const int* __restrict__ idx, const float* __restrict__ tok,
                  const float* __restrict__ pos, u16* __restrict__ x) {
    int gid = blockIdx.x * 256 + threadIdx.x;          // over NM*NE
    int bt = gid / NE, e = gid % NE;
    int t = bt & (NT - 1);
    x[gid] = f2bf(tok[idx[bt] * NE + e] + pos[t * NE + e]);
}

// ---------------- LayerNorm (plain): bf16 x -> bf16 h ----------------------------
__global__ __launch_bounds__(256)
void ln_kernel(const u16* __restrict__ x, const float* __restrict__ g,
               const float* __restrict__ b, u16* __restrict__ out) {
    const int sub = threadIdx.x & 15;
    const int token = blockIdx.x * 16 + (threadIdx.x >> 4);
    const u16* row = x + (size_t)token * NE + sub * 24;
    us8 v0 = *(const us8*)row;
    us8 v1 = *(const us8*)(row + 8);
    us8 v2 = *(const us8*)(row + 16);
    float vals[24];
#pragma unroll
    for (int j = 0; j < 8; ++j) {
        vals[j] = bf2f(v0[j]); vals[8 + j] = bf2f(v1[j]); vals[16 + j] = bf2f(v2[j]);
    }
    float s = 0.f;
#pragma unroll
    for (int j = 0; j < 24; ++j) s += vals[j];
#pragma unroll
    for (int off = 8; off >= 1; off >>= 1) s += __shfl_xor(s, off);
    float mean = s * (1.f / NE);
    float s2 = 0.f;
#pragma unroll
    for (int j = 0; j < 24; ++j) { float d = vals[j] - mean; s2 += d * d; }
#pragma unroll
    for (int off = 8; off >= 1; off >>= 1) s2 += __shfl_xor(s2, off);
    float inv = rsqrtf(s2 * (1.f / NE) + 1e-5f);
    const float* gp = g + sub * 24;
    const float* bp = b + sub * 24;
    us8 o0, o1, o2;
#pragma unroll
    for (int j = 0; j < 8; ++j) {
        o0[j] = f2bf((vals[j] - mean) * inv * gp[j] + bp[j]);
        o1[j] = f2bf((vals[8 + j] - mean) * inv * gp[8 + j] + bp[8 + j]);
        o2[j] = f2bf((vals[16 + j] - mean) * inv * gp[16 + j] + bp[16 + j]);
    }
    u16* orow = out + (size_t)token * NE + sub * 24;
    *(us8*)orow = o0;
    *(us8*)(orow + 8) = o1;
    *(us8*)(orow + 16) = o2;
}

// ---------------- fused residual-add + LayerNorm ---------------------------------
__global__ __launch_bounds__(256)
void ln_add_kernel(u16* __restrict__ x, const u16* __restrict__ c,
                   const float* __restrict__ g, const float* __restrict__ b,
                   u16* __restrict__ out) {
    const int sub = threadIdx.x & 15;
    const int token = blockIdx.x * 16 + (threadIdx.x >> 4);
    const size_t base = (size_t)token * NE + sub * 24;
    u16* xrow = x + base;
    const u16* crow = c + base;
    us8 xv0 = *(const us8*)xrow;
    us8 xv1 = *(const us8*)(xrow + 8);
    us8 xv2 = *(const us8*)(xrow + 16);
    us8 cv0 = *(const us8*)crow;
    us8 cv1 = *(const us8*)(crow + 8);
    us8 cv2 = *(const us8*)(crow + 16);
    float vals[24];
#pragma unroll
    for (int j = 0; j < 8; ++j) {
        vals[j]      = bf2f(xv0[j]) + bf2f(cv0[j]);
        vals[8 + j]  = bf2f(xv1[j]) + bf2f(cv1[j]);
        vals[16 + j] = bf2f(xv2[j]) + bf2f(cv2[j]);
    }
    us8 nx0, nx1, nx2;
#pragma unroll
    for (int j = 0; j < 8; ++j) {
        nx0[j] = f2bf(vals[j]); nx1[j] = f2bf(vals[8 + j]); nx2[j] = f2bf(vals[16 + j]);
    }
    *(us8*)xrow = nx0;
    *(us8*)(xrow + 8) = nx1;
    *(us8*)(xrow + 16) = nx2;
    float s = 0.f;
#pragma unroll
    for (int j = 0; j < 24; ++j) s += vals[j];
#pragma unroll
    for (int off = 8; off >= 1; off >>= 1) s += __shfl_xor(s, off);
    float mean = s * (1.f / NE);
    float s2 = 0.f;
#pragma unroll
    for (int j = 0; j < 24; ++j) { float d = vals[j] - mean; s2 += d * d; }
#pragma unroll
    for (int off = 8; off >= 1; off >>= 1) s2 += __shfl_xor(s2, off);
    float inv = rsqrtf(s2 * (1.f / NE) + 1e-5f);
    const float* gp = g + sub * 24;
    const float* bp = b + sub * 24;
    us8 o0, o1, o2;
#pragma unroll
    for (int j = 0; j < 8; ++j) {
        o0[j] = f2bf((vals[j] - mean) * inv * gp[j] + bp[j]);
        o1[j] = f2bf((vals[8 + j] - mean) * inv * gp[8 + j] + bp[8 + j]);
        o2[j] = f2bf((vals[16 + j] - mean) * inv * gp[16 + j] + bp[16 + j]);
    }
    u16* orow = out + base;
    *(us8*)orow = o0;
    *(us8*)(orow + 8) = o1;
    *(us8*)(orow + 16) = o2;
}

// ---------------- weight conversion -----------------------------------------------
__global__ __launch_bounds__(256)
void convQKV_kernel(const float* __restrict__ Wq, const float* __restrict__ Wk,
                    const float* __restrict__ Wv, u16* __restrict__ dst) {
    int i = blockIdx.x * 256 + threadIdx.x;            // over NL*3*NH*NE*NHS
    int s = i & 63; int rest = i >> 6;
    int e = rest % NE; rest /= NE;
    int hh = rest % NH; rest /= NH;
    int which = rest % 3; int l = rest / 3;
    const float* W = which == 0 ? Wq : which == 1 ? Wk : Wv;
    float v = W[((size_t)(l * NH + hh) * NE + e) * NHS + s];
    dst[((size_t)l * 3 * NE + which * NE + hh * NHS + s) * NE + e] = f2bf(v);
}
__global__ __launch_bounds__(256)
void convT_kernel(const float* __restrict__ src, u16* __restrict__ dst,
                  int K, int N) {
    const float* s = src + (size_t)blockIdx.y * K * N;
    u16* d = dst + (size_t)blockIdx.y * K * N;
    int i = blockIdx.x * 256 + threadIdx.x;
    if (i >= K * N) return;
    int k = i / N, n = i % N;
    d[(size_t)n * K + k] = f2bf(s[i]);
}
__global__ __launch_bounds__(256)
void convLM_kernel(const float* __restrict__ Wlm, u16* __restrict__ dst) {
    int i = blockIdx.x * 256 + threadIdx.x;            // over 80*NE
    if (i >= 80 * NE) return;
    int n = i / NE, k = i % NE;
    dst[i] = f2bf(n < NV ? Wlm[(size_t)k * NV + n] : 0.f);
}

// ---------------- 128x64 MFMA core, double-buffered -------------------------------
static __device__ __forceinline__ void gemm64_core(
        const u16* __restrict__ A, const u16* __restrict__ BT,
        int m0, int n0, int K, f32x4 acc[4][2]) {
    __shared__ __align__(16) u16 smA[2][128 * 32];
    __shared__ __align__(16) u16 smB[2][64 * 32];
    const int tid = threadIdx.x;
    const int wv = tid >> 6, lane = tid & 63;
    const int wm = wv & 1, wn = wv >> 1;
    const int quad = lane >> 4, l16 = lane & 15;
    const int c0 = tid, c1 = tid + 256;
    const size_t aoff0 = (size_t)(m0 + (c0 >> 2)) * K + ((c0 & 3) << 3);
    const size_t aoff1 = (size_t)(m0 + (c1 >> 2)) * K + ((c1 & 3) << 3);
    const size_t boff0 = (size_t)(n0 + (c0 >> 2)) * K + ((c0 & 3) << 3);
    llds16(A + aoff0, smA[0] + c0 * 8);
    llds16(A + aoff1, smA[0] + c1 * 8);
    llds16(BT + boff0, smB[0] + c0 * 8);
    __syncthreads();
    const int nk = K >> 5;
    for (int ki = 0; ki < nk; ++ki) {
        const int cur = ki & 1, nxt = cur ^ 1;
        if (ki + 1 < nk) {
            const int k0 = (ki + 1) << 5;
            llds16(A + aoff0 + k0, smA[nxt] + c0 * 8);
            llds16(A + aoff1 + k0, smA[nxt] + c1 * 8);
            llds16(BT + boff0 + k0, smB[nxt] + c0 * 8);
        }
        mfma_in8 af[4], bf[2];
#pragma unroll
        for (int im = 0; im < 4; ++im)
            af[im] = *(const mfma_in8*)&smA[cur][(wm * 64 + im * 16 + l16) * 32 + quad * 8];
#pragma unroll
        for (int in = 0; in < 2; ++in)
            bf[in] = *(const mfma_in8*)&smB[cur][(wn * 32 + in * 16 + l16) * 32 + quad * 8];
#pragma unroll
        for (int im = 0; im < 4; ++im)
#pragma unroll
            for (int in = 0; in < 2; ++in)
                acc[im][in] = __builtin_amdgcn_mfma_f32_16x16x32_bf16(
                    af[im], bf[in], acc[im][in], 0, 0, 0);
        __syncthreads();
    }
}

// ---------------- 64x64 MFMA core, double-buffered (max residency) ---------------
static __device__ __forceinline__ void gemm6464_core(
        const u16* __restrict__ A, const u16* __restrict__ BT,
        int m0, int n0, int K, f32x4 acc[2][2]) {
    __shared__ __align__(16) u16 smA[2][64 * 32];
    __shared__ __align__(16) u16 smB[2][64 * 32];
    const int tid = threadIdx.x;
    const int wv = tid >> 6, lane = tid & 63;
    const int wm = wv & 1, wn = wv >> 1;
    const int quad = lane >> 4, l16 = lane & 15;
    const size_t aoff = (size_t)(m0 + (tid >> 2)) * K + ((tid & 3) << 3);
    const size_t boff = (size_t)(n0 + (tid >> 2)) * K + ((tid & 3) << 3);
    llds16(A + aoff, smA[0] + tid * 8);
    llds16(BT + boff, smB[0] + tid * 8);
    __syncthreads();
    const int nk = K >> 5;
    for (int ki = 0; ki < nk; ++ki) {
        const int cur = ki & 1, nxt = cur ^ 1;
        if (ki + 1 < nk) {
            const int k0 = (ki + 1) << 5;
            llds16(A + aoff + k0, smA[nxt] + tid * 8);
            llds16(BT + boff + k0, smB[nxt] + tid * 8);
        }
        mfma_in8 af[2], bf[2];
#pragma unroll
        for (int im = 0; im < 2; ++im)
            af[im] = *(const mfma_in8*)&smA[cur][(wm * 32 + im * 16 + l16) * 32 + quad * 8];
#pragma unroll
        for (int in = 0; in < 2; ++in)
            bf[in] = *(const mfma_in8*)&smB[cur][(wn * 32 + in * 16 + l16) * 32 + quad * 8];
#pragma unroll
        for (int im = 0; im < 2; ++im)
#pragma unroll
            for (int in = 0; in < 2; ++in)
                acc[im][in] = __builtin_amdgcn_mfma_f32_16x16x32_bf16(
                    af[im], bf[in], acc[im][in], 0, 0, 0);
        __syncthreads();
    }
}

// QKV: 128x64 tiles, grid 128*18; scatter to q/k/v [B,H,T,HS]
__global__ __launch_bounds__(256)
void gemm_qkv_f(const u16* __restrict__ A, const u16* __restrict__ BT,
                u16* __restrict__ qout, u16* __restrict__ kout,
                u16* __restrict__ vout) {
    const int nbm = NM >> 7;
    const int bm = blockIdx.x % nbm, bn = blockIdx.x / nbm;   // bn 0..17
    const int m0 = bm << 7, n0 = bn << 6;
    f32x4 acc[4][2] = {};
    gemm64_core(A, BT, m0, n0, NE, acc);
    const int lane = threadIdx.x & 63, wv = threadIdx.x >> 6;
    const int wm = wv & 1, wn = wv >> 1;
    const int quad = lane >> 4, l16 = lane & 15;
#pragma unroll
    for (int im = 0; im < 4; ++im)
#pragma unroll
        for (int in = 0; in < 2; ++in)
#pragma unroll
            for (int r = 0; r < 4; ++r) {
                int row = m0 + wm * 64 + im * 16 + quad * 4 + r;
                int col = n0 + wn * 32 + in * 16 + l16;
                int which = col / NE, j = col % NE;
                int hh = j >> 6, s = j & 63;
                int bb = row >> 8, tt = row & 255;
                u16* dst = (which == 0) ? qout : (which == 1) ? kout : vout;
                dst[((((size_t)bb * NH + hh) << 8) + tt) * NHS + s] =
                    f2bf(acc[im][in][r]);
            }
}

// up/relu: 128x64 tiles, grid 128*24
__global__ __launch_bounds__(256)
void gemm_relu_f(const u16* __restrict__ A, const u16* __restrict__ BT,
                 const int N, const int K,
                 const float* __restrict__ bias, u16* __restrict__ outb) {
    const int nbm = NM >> 7;
    const int bm = blockIdx.x % nbm, bn = blockIdx.x / nbm;
    const int m0 = bm << 7, n0 = bn << 6;
    f32x4 acc[4][2] = {};
    gemm64_core(A, BT, m0, n0, K, acc);
    const int lane = threadIdx.x & 63, wv = threadIdx.x >> 6;
    const int wm = wv & 1, wn = wv >> 1;
    const int quad = lane >> 4, l16 = lane & 15;
#pragma unroll
    for (int im = 0; im < 4; ++im)
#pragma unroll
        for (int in = 0; in < 2; ++in)
#pragma unroll
            for (int r = 0; r < 4; ++r) {
                int row = m0 + wm * 64 + im * 16 + quad * 4 + r;
                int col = n0 + wn * 32 + in * 16 + l16;
                outb[(size_t)row * N + col] =
                    f2bf(fmaxf(acc[im][in][r] + bias[col], 0.f));
            }
}

// proj/down: 64x64 tiles, grid 256*6, write-only epilogue cb = C + bias
__global__ __launch_bounds__(256)
void gemm_c_f(const u16* __restrict__ A, const u16* __restrict__ BT,
              const int N, const int K,
              const float* __restrict__ bias, u16* __restrict__ cb) {
    const int nbm = NM >> 6;                   // 256
    const int bm = blockIdx.x % nbm, bn = blockIdx.x / nbm;   // bn 0..5
    const int m0 = bm << 6, n0 = bn << 6;
    f32x4 acc[2][2] = {};
    gemm6464_core(A, BT, m0, n0, K, acc);
    const int lane = threadIdx.x & 63, wv = threadIdx.x >> 6;
    const int wm = wv & 1, wn = wv >> 1;
    const int quad = lane >> 4, l16 = lane & 15;
#pragma unroll
    for (int im = 0; im < 2; ++im)
#pragma unroll
        for (int in = 0; in < 2; ++in)
#pragma unroll
            for (int r = 0; r < 4; ++r) {
                int row = m0 + wm * 32 + im * 16 + quad * 4 + r;
                int col = n0 + wn * 32 + in * 16 + l16;
                cb[(size_t)row * N + col] = f2bf(acc[im][in][r] + bias[col]);
            }
}

// ---------------- fast lmhead ----------------------------------------------------
__global__ __launch_bounds__(256)
void lmhead_f(const u16* __restrict__ xf, const u16* __restrict__ WlmT,
              const float* __restrict__ blm, float* __restrict__ out) {
    const int w = threadIdx.x >> 6, lane = threadIdx.x & 63;
    const int quad = lane >> 4, l16 = lane & 15;
    const int m0 = (blockIdx.x * 4 + w) * 16;
    f32x4 acc[5] = {};
#pragma unroll 2
    for (int k0 = 0; k0 < NE; k0 += 32) {
        mfma_in8 a = *(const mfma_in8*)(xf + (size_t)(m0 + l16) * NE + k0 + quad * 8);
#pragma unroll
        for (int nt = 0; nt < 5; ++nt) {
            mfma_in8 b = *(const mfma_in8*)(WlmT + (size_t)(nt * 16 + l16) * NE + k0 + quad * 8);
            acc[nt] = __builtin_amdgcn_mfma_f32_16x16x32_bf16(a, b, acc[nt], 0, 0, 0);
        }
    }
#pragma unroll
    for (int nt = 0; nt < 5; ++nt) {
        int col = nt * 16 + l16;
        if (col < NV) {
            float bb = blm[col];
#pragma unroll
            for (int r = 0; r < 4; ++r)
                out[(size_t)(m0 + quad * 4 + r) * NV + col] = acc[nt][r] + bb;
        }
    }
}

// ---------------- MFMA flash attention (unchanged) --------------------------------
static __device__ __forceinline__ f32x4 shflx4(f32x4 v, int off) {
    f32x4 r;
#pragma unroll
    for (int i = 0; i < 4; ++i) r[i] = __shfl_xor(v[i], off);
    return r;
}
__global__ __launch_bounds__(256)
void attn_kernel(const u16* __restrict__ q, const u16* __restrict__ k,
                 const u16* __restrict__ v, u16* __restrict__ o) {
    __shared__ __align__(16) u16 sVt[64 * VTP];
    __shared__ __align__(16) u16 sP[4][16 * PSP];
    const int tid = threadIdx.x;
    const int bh = blockIdx.x;
    const int b = bh / NH, hh = bh % NH;
    const size_t base = (size_t)bh << 14;
    {
        const us8* vg = (const us8*)(v + base);
        const int t0 = tid >> 3, c8 = tid & 7;
#pragma unroll
        for (int i = 0; i < 8; ++i) {
            int tt = t0 + i * 32;
            us8 vv = vg[tt * 8 + c8];
#pragma unroll
            for (int j = 0; j < 8; ++j)
                sVt[(c8 * 8 + j) * VTP + tt] = vv[j];
        }
    }
    __syncthreads();
    const int w = tid >> 6, lane = tid & 63;
    const int quad = lane >> 4, l16 = lane & 15;
    mfma_in8 aq[4][2];
#pragma unroll
    for (int mt = 0; mt < 4; ++mt) {
        const int t = w + 4 * mt;
        const u16* qp = q + base + (size_t)(16 * t + l16) * NHS + quad * 8;
        aq[mt][0] = *(const mfma_in8*)qp;
        aq[mt][1] = *(const mfma_in8*)(qp + 32);
    }
    f32x4 oa[4][4] = {};
    f32x4 lsum[4] = {};
    const f32x4 zero = {};
    const int jmax = ((w + 12) >> 1) + 1;
    for (int j = 0; j < jmax; ++j) {
        mfma_in8 bv[4];
#pragma unroll
        for (int nt = 0; nt < 4; ++nt)
            bv[nt] = *(const mfma_in8*)&sVt[(nt * 16 + l16) * VTP + j * 32 + quad * 8];
        mfma_in8 bk[2][2];
#pragma unroll
        for (int nt = 0; nt < 2; ++nt) {
            const u16* kp = k + base + (size_t)(j * 32 + nt * 16 + l16) * NHS + quad * 8;
            bk[nt][0] = *(const mfma_in8*)kp;
            bk[nt][1] = *(const mfma_in8*)(kp + 32);
        }
#pragma unroll
        for (int mt = 0; mt < 4; ++mt) {
            const int t = w + 4 * mt;
            const int jm = t >> 1;
            if (j > jm) continue;
            f32x4 s0 = __builtin_amdgcn_mfma_f32_16x16x32_bf16(aq[mt][0], bk[0][0], zero, 0, 0, 0);
            s0 = __builtin_amdgcn_mfma_f32_16x16x32_bf16(aq[mt][1], bk[0][1], s0, 0, 0, 0);
            f32x4 s1 = __builtin_amdgcn_mfma_f32_16x16x32_bf16(aq[mt][0], bk[1][0], zero, 0, 0, 0);
            s1 = __builtin_amdgcn_mfma_f32_16x16x32_bf16(aq[mt][1], bk[1][1], s1, 0, 0, 0);
            float p[2][4];
            const bool boundary = (j == jm);
#pragma unroll
            for (int nt = 0; nt < 2; ++nt)
#pragma unroll
                for (int r = 0; r < 4; ++r) {
                    float sv = (nt ? s1[r] : s0[r]) * SCALE;
                    float e = __expf(sv);
                    if (boundary) {
                        int u = j * 32 + nt * 16 + l16;
                        int R = 16 * t + quad * 4 + r;
                        if (u > R) e = 0.f;
                    }
                    p[nt][r] = e;
                }
            f32x4 rs;
#pragma unroll
            for (int r = 0; r < 4; ++r) rs[r] = p[0][r] + p[1][r];
            rs += shflx4(rs, 1);
            rs += shflx4(rs, 2);
            rs += shflx4(rs, 4);
            rs += shflx4(rs, 8);
            lsum[mt] += rs;
#pragma unroll
            for (int nt = 0; nt < 2; ++nt)
#pragma unroll
                for (int r = 0; r < 4; ++r)
                    sP[w][(quad * 4 + r) * PSP + nt * 16 + l16] = f2bf(p[nt][r]);
            mfma_in8 ap = *(const mfma_in8*)&sP[w][l16 * PSP + quad * 8];
#pragma unroll
            for (int nt = 0; nt < 4; ++nt)
                oa[mt][nt] = __builtin_amdgcn_mfma_f32_16x16x32_bf16(ap, bv[nt], oa[mt][nt], 0, 0, 0);
        }
    }
#pragma unroll
    for (int mt = 0; mt < 4; ++mt) {
        const int t = w + 4 * mt;
        f32x4 inv;
#pragma unroll
        for (int r = 0; r < 4; ++r) inv[r] = 1.f / lsum[mt][r];
#pragma unroll
        for (int nt = 0; nt < 4; ++nt)
#pragma unroll
            for (int r = 0; r < 4; ++r) {
                int row = 16 * t + quad * 4 + r;
                int col = hh * NHS + nt * 16 + l16;
                o[((size_t)(b * NT + row)) * NE + col] = f2bf(oa[mt][nt][r] * inv[r]);
            }
    }
}

// ---------------- loss ------------------------------------------------------------
__global__ __launch_bounds__(256)
void loss_kernel(const float* __restrict__ logits, const int* __restrict__ targets,
                 float* __restrict__ acc) {
    int t = blockIdx.x * 256 + threadIdx.x;
    const float* row = logits + (size_t)t * NV;
    float mx = -1e30f;
    for (int i = 0; i < NV; ++i) mx = fmaxf(mx, row[i]);
    float se = 0.f;
    for (int i = 0; i < NV; ++i) se += __expf(row[i] - mx);
    float li = __logf(se) + mx - row[targets[t]];
#pragma unroll
    for (int off = 32; off >= 1; off >>= 1) li += __shfl_xor(li, off);
    if ((threadIdx.x & 63) == 0) atomicAdd(acc, li);
}
__global__ void loss_final_kernel(const float* __restrict__ acc, float* __restrict__ out) {
    out[0] = acc[0] * (1.f / (float)NM);
}
__global__ void code_kernel(float* __restrict__ out0, float code) {
    if (threadIdx.x == 0 && blockIdx.x == 0) out0[0] = code;
}

// ================================ host ==========================================
extern "C" void kernel_launch(void* const* d_in, const int* in_sizes, int n_in,
                              void* d_out, int out_size, void* d_ws, size_t ws_size,
                              hipStream_t stream) {
    const int*   idx      = (const int*)d_in[0];
    const int*   targets  = (const int*)d_in[1];
    const float* tok_emb  = (const float*)d_in[2];
    const float* pos_emb  = (const float*)d_in[3];
    const float* Wq       = (const float*)d_in[4];
    const float* Wk       = (const float*)d_in[5];
    const float* Wv       = (const float*)d_in[6];
    const float* Wproj    = (const float*)d_in[7];
    const float* bproj    = (const float*)d_in[8];
    const float* ln1_g    = (const float*)d_in[9];
    const float* ln1_b    = (const float*)d_in[10];
    const float* ln2_g    = (const float*)d_in[11];
    const float* ln2_b    = (const float*)d_in[12];
    const float* W1       = (const float*)d_in[13];
    const float* b1       = (const float*)d_in[14];
    const float* W2       = (const float*)d_in[15];
    const float* b2       = (const float*)d_in[16];
    const float* lnf_g    = (const float*)d_in[17];
    const float* lnf_b    = (const float*)d_in[18];
    const float* Wlm      = (const float*)d_in[19];
    const float* blm      = (const float*)d_in[20];
    float* out = (float*)d_out;

    static const int expect[21] = {
        16384, 16384, 24960, 98304, 884736, 884736, 884736, 884736, 2304,
        2304, 2304, 2304, 2304, 3538944, 9216, 3538944, 2304, 384, 384,
        24960, 65};
    if (n_in < 21) { code_kernel<<<1, 1, 0, stream>>>(out, 990.f); return; }
    for (int i = 0; i < 21; ++i)
        if (in_sizes[i] != expect[i]) {
            code_kernel<<<1, 1, 0, stream>>>(out, 1000.f + 10.f * i);
            return;
        }

    // ---- workspace layout (~117 MB) ----
    char* ws = (char*)d_ws;
    size_t off = 0;
    auto alloc = [&](size_t bytes) -> void* {
        void* p = ws + off;
        off += (bytes + 255) & ~(size_t)255;
        return p;
    };
    const size_t S = (size_t)NM * NE * 2;          // 12.58 MB
    float* lossacc = (float*)alloc(256);
    u16*   x       = (u16*)alloc(S);               // bf16 residual master
    u16*   h       = (u16*)alloc(S);
    u16*   cb      = (u16*)alloc(S);               // GEMM C output (pre-residual)
    u16*   region  = (u16*)alloc(4 * S);           // q|k|v|o, overlaid by ub
    u16*   qb = region;
    u16*   kb = region + NM * NE;
    u16*   vb = region + 2 * (size_t)NM * NE;
    u16*   ob = region + 3 * (size_t)NM * NE;
    u16*   ub = region;
    u16* WqkvT  = (u16*)alloc((size_t)NL * 3 * NE * NE * 2);
    u16* WprojT = (u16*)alloc((size_t)NL * NE * NE * 2);
    u16* W1T    = (u16*)alloc((size_t)NL * NE * 4 * NE * 2);
    u16* W2T    = (u16*)alloc((size_t)NL * NE * 4 * NE * 2);
    u16* WlmT   = (u16*)alloc((size_t)80 * NE * 2);

    if (ws_size < off) { code_kernel<<<1, 1, 0, stream>>>(out, 999.f); return; }

    hipMemsetAsync(lossacc, 0, 4, stream);
    embed_kernel<<<(NM * NE) / 256, 256, 0, stream>>>(idx, tok_emb, pos_emb, x);

    convQKV_kernel<<<(NL * 3 * NH * NE * NHS) / 256, 256, 0, stream>>>(Wq, Wk, Wv, WqkvT);
    convT_kernel<<<dim3((NE * NE + 255) / 256, NL), 256, 0, stream>>>(Wproj, WprojT, NE, NE);
    convT_kernel<<<dim3((NE * 4 * NE + 255) / 256, NL), 256, 0, stream>>>(W1, W1T, NE, 4 * NE);
    convT_kernel<<<dim3((NE * 4 * NE + 255) / 256, NL), 256, 0, stream>>>(W2, W2T, 4 * NE, NE);
    convLM_kernel<<<(80 * NE + 255) / 256, 256, 0, stream>>>(Wlm, WlmT);

    const int gLN = NM / 16;
    const int nbm = NM / 128;      // 128
    const int nbm2 = NM / 64;      // 256
    for (int l = 0; l < NL; ++l) {
        if (l == 0)
            ln_kernel<<<gLN, 256, 0, stream>>>(x, ln1_g, ln1_b, h);
        else
            ln_add_kernel<<<gLN, 256, 0, stream>>>(x, cb, ln1_g + l * NE,
                                                   ln1_b + l * NE, h);
        gemm_qkv_f<<<nbm * (3 * NE / 64), 256, 0, stream>>>(
            h, WqkvT + (size_t)l * 3 * NE * NE, qb, kb, vb);
        attn_kernel<<<NB * NH, 256, 0, stream>>>(qb, kb, vb, ob);
        gemm_c_f<<<nbm2 * (NE / 64), 256, 0, stream>>>(
            ob, WprojT + (size_t)l * NE * NE, NE, NE, bproj + l * NE, cb);
        ln_add_kernel<<<gLN, 256, 0, stream>>>(x, cb, ln2_g + l * NE,
                                               ln2_b + l * NE, h);
        gemm_relu_f<<<nbm * (4 * NE / 64), 256, 0, stream>>>(
            h, W1T + (size_t)l * NE * 4 * NE, 4 * NE, NE, b1 + l * 4 * NE, ub);
        gemm_c_f<<<nbm2 * (NE / 64), 256, 0, stream>>>(
            ub, W2T + (size_t)l * NE * 4 * NE, NE, 4 * NE, b2 + l * NE, cb);
    }

    ln_add_kernel<<<gLN, 256, 0, stream>>>(x, cb, lnf_g, lnf_b, h);
    lmhead_f<<<NM / 64, 256, 0, stream>>>(h, WlmT, blm, out);
    loss_kernel<<<NM / 256, 256, 0, stream>>>(out, targets, lossacc);
    if (out_size > NM * NV)
        loss_final_kernel<<<1, 1, 0, stream>>>(lossacc, out + (size_t)NM * NV);
}